// Round 3
// baseline (242.492 us; speedup 1.0000x reference)
//
#include <hip/hip_runtime.h>

#define T_GT 64

typedef unsigned int u32;
typedef unsigned long long u64;

// ---------------------------------------------------------------------------
// Prep 1: per-(b,t) gt areas (scalar unit has no FP; precompute so the hot
// loops can s_load them).
// ---------------------------------------------------------------------------
__global__ void areas_kernel(const float4* __restrict__ gt_boxes,
                             float* __restrict__ areas, int n) {
    int i = blockIdx.x * blockDim.x + threadIdx.x;
    if (i >= n) return;
    float4 gb = gt_boxes[i];
    areas[i] = (gb.z - gb.x) * (gb.w - gb.y);
}

// ---------------------------------------------------------------------------
// Prep 2: unpack priors cx,cy,w,h -> xyxy + area (ref rounds xyxy first, then
// takes area from the rounded coords; 0.5f*w == w/2 exactly).
// ---------------------------------------------------------------------------
__global__ void prior_prep(const float4* __restrict__ priors,
                           float4* __restrict__ pxyxy,
                           float* __restrict__ parea, int P) {
    int p = blockIdx.x * blockDim.x + threadIdx.x;
    if (p >= P) return;
    float4 pr = priors[p];
    float px0 = pr.x - 0.5f * pr.z;
    float py0 = pr.y - 0.5f * pr.w;
    float px1 = pr.x + 0.5f * pr.z;
    float py1 = pr.y + 0.5f * pr.w;
    pxyxy[p] = make_float4(px0, py0, px1, py1);
    parea[p] = (px1 - px0) * (py1 - py0);
}

// ---------------------------------------------------------------------------
// Kernel A: per (b,t) argmax_p IoU, first-index ties. lane = t; the whole
// wave shares each prior p -> wave-uniform s_load of pxyxy/parea. Chunked
// over p; chunks merge via atomicMax on packed (q_bits<<32)|~p (q>=0 so
// float bits are u32-monotone; ~p = first-index tie-break).
// ---------------------------------------------------------------------------
__global__ void best_prior_flat(const float4* __restrict__ pxyxy,
                                const float* __restrict__ parea,
                                const float4* __restrict__ gt_boxes,
                                u64* __restrict__ bp,
                                int P, int chunks, int chunk_len) {
    const int lane  = threadIdx.x & 63;
    const int wave  = threadIdx.x >> 6;
    const int b     = blockIdx.y;
    const int chunk = blockIdx.x * (blockDim.x >> 6) + wave;
    if (chunk >= chunks) return;

    int p0 = chunk * chunk_len;
    int p1 = p0 + chunk_len;
    if (p1 > P) p1 = P;
    if (p0 >= p1) return;

    const float4 gb = gt_boxes[b * T_GT + lane];
    const float garea = (gb.z - gb.x) * (gb.w - gb.y);

    float best_v = -1.0f;
    u32   best_p = 0u;
    #pragma unroll 8
    for (int p = p0; p < p1; ++p) {
        const float4 pb = pxyxy[p];     // wave-uniform -> s_load_dwordx4
        const float  pa = parea[p];     // wave-uniform -> s_load_dword
        const float ltx = fmaxf(gb.x, pb.x);
        const float lty = fmaxf(gb.y, pb.y);
        const float rbx = fminf(gb.z, pb.z);
        const float rby = fminf(gb.w, pb.w);
        const float wx = fmaxf(rbx - ltx, 0.0f);
        const float wy = fmaxf(rby - lty, 0.0f);
        const float inter = wx * wy;
        const float uni = (garea + pa) - inter;   // ref op order
        const float q = inter / uni;              // IEEE f32 divide
        if (q > best_v) { best_v = q; best_p = (u32)p; }
    }
    const u64 packed = ((u64)__float_as_uint(best_v) << 32)
                     | (u64)(0xFFFFFFFFu - best_p);
    atomicMax(&bp[b * T_GT + lane], packed);
}

// ---------------------------------------------------------------------------
// Kernel B: per (b,p) argmax_t IoU (first-index), threshold, encode loc.
// gt data read with block-uniform indices -> s_load, no LDS pipe traffic.
// ---------------------------------------------------------------------------
__global__ void match_kernel(const float4* __restrict__ priors,
                             const float4* __restrict__ gt_boxes,
                             const float* __restrict__ areas,
                             const int* __restrict__ gt_labels,
                             float* __restrict__ out_loc,   // (B, P, 4)
                             float* __restrict__ out_lbl,   // (B, P) as float
                             int P) {
    const int b = blockIdx.y;
    const int p = blockIdx.x * blockDim.x + threadIdx.x;
    if (p >= P) return;

    const float4 pr = priors[p];               // cx, cy, w, h (per-lane)
    const float px0 = pr.x - 0.5f * pr.z;
    const float py0 = pr.y - 0.5f * pr.w;
    const float px1 = pr.x + 0.5f * pr.z;
    const float py1 = pr.y + 0.5f * pr.w;
    const float parea = (px1 - px0) * (py1 - py0);

    const float4* __restrict__ gbase = gt_boxes + b * T_GT;
    const float*  __restrict__ abase = areas    + b * T_GT;

    float best_v = -1.0f;
    int   best_t = 0;
    #pragma unroll 8
    for (int t = 0; t < T_GT; ++t) {
        const float4 gb = gbase[t];            // block-uniform -> s_load
        const float  ar = abase[t];            // block-uniform -> s_load
        const float ltx = fmaxf(gb.x, px0);
        const float lty = fmaxf(gb.y, py0);
        const float rbx = fminf(gb.z, px1);
        const float rby = fminf(gb.w, py1);
        const float wx = fmaxf(rbx - ltx, 0.0f);
        const float wy = fmaxf(rby - lty, 0.0f);
        const float inter = wx * wy;
        const float uni = (ar + parea) - inter;
        const float q = inter / uni;                 // IEEE f32 divide
        if (q > best_v) { best_v = q; best_t = t; }  // strict > keeps first t
    }

    const int lbl = (best_v < 0.5f) ? 0 : gt_labels[b * T_GT + best_t];

    const float4 mb  = gbase[best_t];          // per-lane, L1-hot (1 KB)
    const float  bcx = (mb.x + mb.z) * 0.5f;
    const float  bcy = (mb.y + mb.w) * 0.5f;
    const float  bw  = mb.z - mb.x;
    const float  bh  = mb.w - mb.y;

    float4 loc;
    loc.x = (bcx - pr.x) / (0.1f * pr.z);
    loc.y = (bcy - pr.y) / (0.1f * pr.w);
    loc.z = logf(bw / pr.z) / 0.2f;
    loc.w = logf(bh / pr.w) / 0.2f;

    ((float4*)out_loc)[(size_t)b * P + p] = loc;
    out_lbl[(size_t)b * P + p] = (float)lbl;
}

// ---------------------------------------------------------------------------
// Kernel C: matches[best_prior[t]] = t override (numpy last-wins on dups;
// matched_val = 2.0 so label always kept). One block per image, 64 threads.
// ---------------------------------------------------------------------------
__global__ void fixup_kernel(const float4* __restrict__ priors,
                             const float4* __restrict__ gt_boxes,
                             const int* __restrict__ gt_labels,
                             const u64* __restrict__ bp,
                             float* __restrict__ out_loc,
                             float* __restrict__ out_lbl,
                             int P) {
    __shared__ u32 s_p[T_GT];
    const int b = blockIdx.x;
    const int t = threadIdx.x;
    const u32 p = 0xFFFFFFFFu - (u32)(bp[b * T_GT + t] & 0xFFFFFFFFull);
    s_p[t] = p;
    __syncthreads();
    for (int u = t + 1; u < T_GT; ++u)
        if (s_p[u] == p) return;      // a later t overrides this prior

    const float4 pr = priors[p];
    const float4 mb = gt_boxes[b * T_GT + t];
    const float  bcx = (mb.x + mb.z) * 0.5f;
    const float  bcy = (mb.y + mb.w) * 0.5f;
    const float  bw  = mb.z - mb.x;
    const float  bh  = mb.w - mb.y;

    float4 loc;
    loc.x = (bcx - pr.x) / (0.1f * pr.z);
    loc.y = (bcy - pr.y) / (0.1f * pr.w);
    loc.z = logf(bw / pr.z) / 0.2f;
    loc.w = logf(bh / pr.w) / 0.2f;

    ((float4*)out_loc)[(size_t)b * P + p] = loc;
    out_lbl[(size_t)b * P + p] = (float)gt_labels[b * T_GT + t];
}

extern "C" void kernel_launch(void* const* d_in, const int* in_sizes, int n_in,
                              void* d_out, int out_size, void* d_ws, size_t ws_size,
                              hipStream_t stream) {
    const float4* priors    = (const float4*)d_in[0];   // (P, 4) f32
    const float4* gt_boxes  = (const float4*)d_in[1];   // (B, T, 4) f32
    const int*    gt_labels = (const int*)d_in[2];      // (B, T) i32

    const int P = in_sizes[0] / 4;
    const int B = in_sizes[2] / T_GT;
    const int BT = B * T_GT;

    float* out_loc = (float*)d_out;
    float* out_lbl = out_loc + (size_t)B * P * 4;

    // workspace layout (round-2 proved ws >= ~2.02 MB on this harness)
    char* ws = (char*)d_ws;
    u64*    bp     = (u64*)ws;                               // BT u64
    float*  areas  = (float*)(ws + (size_t)BT * 8);          // BT f32
    float*  parea  = areas + BT;                             // P f32
    size_t  xy_off = ((size_t)BT * 8 + (size_t)BT * 4 + (size_t)P * 4 + 15) & ~(size_t)15;
    float4* pxyxy  = (float4*)(ws + xy_off);                 // P float4

    hipMemsetAsync(bp, 0, (size_t)BT * 8, stream);

    areas_kernel<<<(BT + 255) / 256, 256, 0, stream>>>(gt_boxes, areas, BT);
    prior_prep<<<(P + 255) / 256, 256, 0, stream>>>(priors, pxyxy, parea, P);

    // Kernel A: 1024 chunks/image, 4 waves/block -> 16 waves/SIMD total
    const int chunks = 1024;
    const int chunk_len = (P + chunks - 1) / chunks;
    dim3 gA(chunks / 4, B);
    best_prior_flat<<<gA, 256, 0, stream>>>(pxyxy, parea, gt_boxes, bp,
                                            P, chunks, chunk_len);

    dim3 gB((P + 255) / 256, B);
    match_kernel<<<gB, 256, 0, stream>>>(priors, gt_boxes, areas, gt_labels,
                                         out_loc, out_lbl, P);
    fixup_kernel<<<B, T_GT, 0, stream>>>(priors, gt_boxes, gt_labels, bp,
                                         out_loc, out_lbl, P);
}

// Round 4
// 177.873 us; speedup vs baseline: 1.3633x; 1.3633x over previous
//
#include <hip/hip_runtime.h>

#define T_GT 64

typedef unsigned int u32;
typedef unsigned long long u64;

// ---------------------------------------------------------------------------
// Fused kernel: thread = (b, p). Computes each IoU ONCE and feeds both
// reductions:
//   - match: per-(b,p) argmax over t  -> pack (q_bits<<32)|(63-t), max
//     (first-index tie-break regardless of visit order)
//   - best_prior: per-(b,t) argmax over p -> systolic ring. Lane l starts
//     with gt t=l; at iter i lane l evaluates t=(l+i)&63; gt box + per-t
//     accumulator rotate left 1 lane each iter so the acc follows its t.
//     After 64 iters lane l holds the wave max for t=l; merge 4 waves in
//     LDS, one atomicMax per t: pack (q_bits<<32)|(~p) = numpy first-index.
// q >= 0 so float bits are u32-monotone. All FP ops mirror the ref's exact
// order (IEEE f32 divide, no fast-math) so selection is bit-exact vs numpy.
// ---------------------------------------------------------------------------
__global__ void __launch_bounds__(256)
fused_match(const float4* __restrict__ priors,
            const float4* __restrict__ gt_boxes,
            const int* __restrict__ gt_labels,
            u64* __restrict__ bp,
            float* __restrict__ out_loc,   // (B, P, 4)
            float* __restrict__ out_lbl,   // (B, P) as float
            int P) {
    __shared__ u64 s_acc[4][T_GT];

    const int tid   = threadIdx.x;
    const int lane  = tid & 63;
    const int wv    = tid >> 6;
    const int b     = blockIdx.y;
    const int p_raw = blockIdx.x * blockDim.x + tid;
    const int p     = min(p_raw, P - 1);   // clamp: all lanes stay shfl-active
                                           // (duplicate of prior P-1 is a
                                           // no-op for a max reduction)

    const float4 pr = priors[p];           // cx, cy, w, h — coalesced
    const float px0 = pr.x - 0.5f * pr.z;  // == cx - w/2 exactly
    const float py0 = pr.y - 0.5f * pr.w;
    const float px1 = pr.x + 0.5f * pr.z;
    const float py1 = pr.y + 0.5f * pr.w;
    const float parea = (px1 - px0) * (py1 - py0);   // ref: area from rounded xyxy
    const u64 npk = (u64)(0xFFFFFFFFu - (u32)p);     // ~p for best-prior pack

    // gt box for t = lane (rotates through the ring)
    float4 gb = gt_boxes[b * T_GT + lane];

    u64 acc   = 0;            // best-prior acc for the t currently at this lane
    u64 mbest = 0;            // match acc (pack >= 63 at t=0, so init 0 is safe)
    int rt    = 63 - lane;    // 63 - t for this lane's current t
    const int src = (lane + 1) & 63;   // rotate-left-by-1 source lane

    #pragma unroll 8
    for (int i = 0; i < T_GT; ++i) {
        const float gar = (gb.z - gb.x) * (gb.w - gb.y);   // ref area1
        const float ltx = fmaxf(gb.x, px0);
        const float lty = fmaxf(gb.y, py0);
        const float rbx = fminf(gb.z, px1);
        const float rby = fminf(gb.w, py1);
        const float wx = fmaxf(rbx - ltx, 0.0f);
        const float wy = fmaxf(rby - lty, 0.0f);
        const float inter = wx * wy;
        const float uni = (gar + parea) - inter;   // ref op order
        const float q = inter / uni;               // IEEE f32 divide
        const u64 qh = (u64)__float_as_uint(q) << 32;

        const u64 mp = qh | (u32)rt;               // match pack
        if (mp > mbest) mbest = mp;
        const u64 ap = qh | npk;                   // best-prior pack
        if (ap > acc) acc = ap;

        // rotate ring left by 1 (acc follows its t; gb moves to next t)
        acc  = __shfl(acc, src);
        gb.x = __shfl(gb.x, src);
        gb.y = __shfl(gb.y, src);
        gb.z = __shfl(gb.z, src);
        gb.w = __shfl(gb.w, src);
        rt   = (rt - 1) & 63;
    }

    // after 64 rotations, acc at lane l corresponds to t = l
    s_acc[wv][lane] = acc;
    __syncthreads();
    if (tid < T_GT) {
        u64 m = s_acc[0][tid];
        #pragma unroll
        for (int w = 1; w < 4; ++w) {
            const u64 v = s_acc[w][tid];
            if (v > m) m = v;
        }
        atomicMax(&bp[b * T_GT + tid], m);
    }

    if (p_raw >= P) return;

    const int   t_best = 63 - (int)(mbest & 63u);
    const float q_best = __uint_as_float((u32)(mbest >> 32));
    const int   lbl = (q_best < 0.5f) ? 0 : gt_labels[b * T_GT + t_best];

    const float4 mb  = gt_boxes[b * T_GT + t_best];   // L1-hot 1 KB gather
    const float  bcx = (mb.x + mb.z) * 0.5f;
    const float  bcy = (mb.y + mb.w) * 0.5f;
    const float  bw  = mb.z - mb.x;
    const float  bh  = mb.w - mb.y;

    float4 loc;
    loc.x = (bcx - pr.x) / (0.1f * pr.z);
    loc.y = (bcy - pr.y) / (0.1f * pr.w);
    loc.z = logf(bw / pr.z) / 0.2f;
    loc.w = logf(bh / pr.w) / 0.2f;

    ((float4*)out_loc)[(size_t)b * P + p_raw] = loc;
    out_lbl[(size_t)b * P + p_raw] = (float)lbl;
}

// ---------------------------------------------------------------------------
// Fixup: matches[best_prior[t]] = t override (numpy last-wins on duplicate
// best_prior values; matched_val = 2.0 so the label is always kept).
// One block per image, 64 threads.
// ---------------------------------------------------------------------------
__global__ void fixup_kernel(const float4* __restrict__ priors,
                             const float4* __restrict__ gt_boxes,
                             const int* __restrict__ gt_labels,
                             const u64* __restrict__ bp,
                             float* __restrict__ out_loc,
                             float* __restrict__ out_lbl,
                             int P) {
    __shared__ u32 s_p[T_GT];
    const int b = blockIdx.x;
    const int t = threadIdx.x;
    const u32 p = 0xFFFFFFFFu - (u32)(bp[b * T_GT + t] & 0xFFFFFFFFull);
    s_p[t] = p;
    __syncthreads();
    for (int u = t + 1; u < T_GT; ++u)
        if (s_p[u] == p) return;      // a later t overrides this prior

    const float4 pr = priors[p];
    const float4 mb = gt_boxes[b * T_GT + t];
    const float  bcx = (mb.x + mb.z) * 0.5f;
    const float  bcy = (mb.y + mb.w) * 0.5f;
    const float  bw  = mb.z - mb.x;
    const float  bh  = mb.w - mb.y;

    float4 loc;
    loc.x = (bcx - pr.x) / (0.1f * pr.z);
    loc.y = (bcy - pr.y) / (0.1f * pr.w);
    loc.z = logf(bw / pr.z) / 0.2f;
    loc.w = logf(bh / pr.w) / 0.2f;

    ((float4*)out_loc)[(size_t)b * P + p] = loc;
    out_lbl[(size_t)b * P + p] = (float)gt_labels[b * T_GT + t];
}

extern "C" void kernel_launch(void* const* d_in, const int* in_sizes, int n_in,
                              void* d_out, int out_size, void* d_ws, size_t ws_size,
                              hipStream_t stream) {
    const float4* priors    = (const float4*)d_in[0];   // (P, 4) f32
    const float4* gt_boxes  = (const float4*)d_in[1];   // (B, T, 4) f32
    const int*    gt_labels = (const int*)d_in[2];      // (B, T) i32

    const int P  = in_sizes[0] / 4;
    const int B  = in_sizes[2] / T_GT;
    const int BT = B * T_GT;

    float* out_loc = (float*)d_out;
    float* out_lbl = out_loc + (size_t)B * P * 4;

    u64* bp = (u64*)d_ws;   // BT packed u64
    hipMemsetAsync(bp, 0, (size_t)BT * sizeof(u64), stream);

    dim3 g((P + 255) / 256, B);
    fused_match<<<g, 256, 0, stream>>>(priors, gt_boxes, gt_labels, bp,
                                       out_loc, out_lbl, P);
    fixup_kernel<<<B, T_GT, 0, stream>>>(priors, gt_boxes, gt_labels, bp,
                                         out_loc, out_lbl, P);
}

// Round 5
// 176.827 us; speedup vs baseline: 1.3714x; 1.0059x over previous
//
#include <hip/hip_runtime.h>

#define T_GT 64
#define KP 4          // priors per thread

typedef unsigned int u32;
typedef unsigned long long u64;

// ---------------------------------------------------------------------------
// Fused kernel: thread = (b, 4 consecutive priors). Each IoU computed ONCE:
//   - match: per-prior argmax over t -> pack (q_bits<<32)|(63-t), u64 max
//     (first-index tie-break independent of ring visit order)
//   - best_prior: per-(b,t) argmax over p via systolic ring: lane l holds gt
//     t=l at start; at step i lane l evaluates t=(l+i)&63 against its 4
//     priors; the per-t accumulator rotates with its t. Pack
//     (q_bits<<32)|(~p) = numpy first-index semantics, order-independent.
//     Block-merged partials written non-atomically to ws (no memset needed).
// q >= 0 so float bits are u32-monotone. FP ops mirror the ref's exact order
// (IEEE f32 divide, no fast-math) so all selection is bit-exact vs numpy.
// ---------------------------------------------------------------------------
__global__ void __launch_bounds__(256)
fused_match(const float4* __restrict__ priors,
            const float4* __restrict__ gt_boxes,
            const int* __restrict__ gt_labels,
            u64* __restrict__ part,        // (B, NG, 64) block partials
            float* __restrict__ out_loc,   // (B, P, 4)
            float* __restrict__ out_lbl,   // (B, P) as float
            int P, int NG) {
    __shared__ u64 s_acc[4][T_GT];

    const int tid  = threadIdx.x;
    const int lane = tid & 63;
    const int wv   = tid >> 6;
    const int b    = blockIdx.y;
    const int tb   = blockIdx.x * blockDim.x + tid;

    // load 4 consecutive priors (thread streams 64B; wave streams 4KB)
    float px0[KP], py0[KP], px1[KP], py1[KP], pa[KP];
    u32 pclamped[KP];
    #pragma unroll
    for (int j = 0; j < KP; ++j) {
        const int p = min(tb * KP + j, P - 1);   // clamp: dup of P-1 is a
        pclamped[j] = (u32)p;                    // no-op for max reductions
        const float4 pr = priors[p];
        px0[j] = pr.x - 0.5f * pr.z;             // == cx - w/2 exactly
        py0[j] = pr.y - 0.5f * pr.w;
        px1[j] = pr.x + 0.5f * pr.z;
        py1[j] = pr.y + 0.5f * pr.w;
        pa[j]  = (px1[j] - px0[j]) * (py1[j] - py0[j]);  // ref: area from xyxy
    }

    float4 gb = gt_boxes[b * T_GT + lane];   // gt for current t (rotates)

    u64 acc = 0;                  // best-prior acc for the t at this lane
    u64 mbest[KP];                // per-prior match acc
    #pragma unroll
    for (int j = 0; j < KP; ++j) mbest[j] = 0;
    int rt = 63 - lane;           // 63 - t for this lane's current t
    const int src = (lane + 1) & 63;

    #pragma unroll 4
    for (int i = 0; i < T_GT; ++i) {
        const float gar = (gb.z - gb.x) * (gb.w - gb.y);
        u64 step = 0;
        #pragma unroll
        for (int j = 0; j < KP; ++j) {
            const float ltx = fmaxf(gb.x, px0[j]);
            const float lty = fmaxf(gb.y, py0[j]);
            const float rbx = fminf(gb.z, px1[j]);
            const float rby = fminf(gb.w, py1[j]);
            const float wx = fmaxf(rbx - ltx, 0.0f);
            const float wy = fmaxf(rby - lty, 0.0f);
            const float inter = wx * wy;
            const float uni = (gar + pa[j]) - inter;   // ref op order
            const float q = inter / uni;               // IEEE f32 divide
            const u64 qh = (u64)__float_as_uint(q) << 32;
            const u64 mp = qh | (u32)rt;
            if (mp > mbest[j]) mbest[j] = mp;
            const u64 ap = qh | (u64)(0xFFFFFFFFu - pclamped[j]);
            if (ap > step) step = ap;
        }
        if (step > acc) acc = step;
        // rotate ring left by 1 (acc follows its t; gb advances to next t)
        acc  = __shfl(acc, src);
        gb.x = __shfl(gb.x, src);
        gb.y = __shfl(gb.y, src);
        gb.z = __shfl(gb.z, src);
        gb.w = __shfl(gb.w, src);
        rt   = (rt - 1) & 63;
    }

    // after 64 rotations, acc at lane l corresponds to t = l
    s_acc[wv][lane] = acc;
    __syncthreads();
    if (tid < T_GT) {
        u64 m = s_acc[0][tid];
        #pragma unroll
        for (int w = 1; w < 4; ++w) {
            const u64 v = s_acc[w][tid];
            if (v > m) m = v;
        }
        part[((size_t)b * NG + blockIdx.x) * T_GT + tid] = m;
    }

    // epilogue: decode match, encode loc (cx,cy,w,h reconstructed from xyxy;
    // ulp-level drift only — selection uses exact packed q)
    #pragma unroll
    for (int j = 0; j < KP; ++j) {
        const int p = tb * KP + j;
        if (p >= P) break;
        const int   t_best = 63 - (int)(mbest[j] & 63u);
        const float q_best = __uint_as_float((u32)(mbest[j] >> 32));
        const int   lbl = (q_best < 0.5f) ? 0 : gt_labels[b * T_GT + t_best];

        const float4 mb  = gt_boxes[b * T_GT + t_best];   // L1-hot 1 KB
        const float  bcx = (mb.x + mb.z) * 0.5f;
        const float  bcy = (mb.y + mb.w) * 0.5f;
        const float  bw  = mb.z - mb.x;
        const float  bh  = mb.w - mb.y;

        const float cx = (px0[j] + px1[j]) * 0.5f;
        const float cy = (py0[j] + py1[j]) * 0.5f;
        const float w  = px1[j] - px0[j];
        const float h  = py1[j] - py0[j];

        float4 loc;
        loc.x = (bcx - cx) / (0.1f * w);
        loc.y = (bcy - cy) / (0.1f * h);
        loc.z = logf(bw / w) / 0.2f;
        loc.w = logf(bh / h) / 0.2f;

        ((float4*)out_loc)[(size_t)b * P + p] = loc;
        out_lbl[(size_t)b * P + p] = (float)lbl;
    }
}

// ---------------------------------------------------------------------------
// Fixup: reduce block partials per (b,t), then apply
// matches[best_prior[t]] = t (numpy last-wins on duplicate best_prior;
// matched_val = 2.0 so the label is always kept). One block per image.
// ---------------------------------------------------------------------------
__global__ void __launch_bounds__(256)
fixup_kernel(const float4* __restrict__ priors,
             const float4* __restrict__ gt_boxes,
             const int* __restrict__ gt_labels,
             const u64* __restrict__ part,
             float* __restrict__ out_loc,
             float* __restrict__ out_lbl,
             int P, int NG) {
    __shared__ u64 s_m[4][T_GT];
    __shared__ u32 s_p[T_GT];
    const int b   = blockIdx.x;
    const int tid = threadIdx.x;
    const int t   = tid & 63;
    const int w   = tid >> 6;

    u64 m = 0;
    for (int g = w; g < NG; g += 4) {
        const u64 v = part[((size_t)b * NG + g) * T_GT + t];
        if (v > m) m = v;
    }
    s_m[w][t] = m;
    __syncthreads();
    if (tid >= T_GT) return;

    m = s_m[0][t];
    #pragma unroll
    for (int i = 1; i < 4; ++i) {
        const u64 v = s_m[i][t];
        if (v > m) m = v;
    }
    const u32 p = 0xFFFFFFFFu - (u32)(m & 0xFFFFFFFFull);
    s_p[t] = p;
    __syncthreads();
    for (int u = t + 1; u < T_GT; ++u)
        if (s_p[u] == p) return;      // a later t overrides this prior

    const float4 pr = priors[p];
    const float4 mb = gt_boxes[b * T_GT + t];
    const float  bcx = (mb.x + mb.z) * 0.5f;
    const float  bcy = (mb.y + mb.w) * 0.5f;
    const float  bw  = mb.z - mb.x;
    const float  bh  = mb.w - mb.y;

    float4 loc;
    loc.x = (bcx - pr.x) / (0.1f * pr.z);
    loc.y = (bcy - pr.y) / (0.1f * pr.w);
    loc.z = logf(bw / pr.z) / 0.2f;
    loc.w = logf(bh / pr.w) / 0.2f;

    ((float4*)out_loc)[(size_t)b * P + p] = loc;
    out_lbl[(size_t)b * P + p] = (float)gt_labels[b * T_GT + t];
}

extern "C" void kernel_launch(void* const* d_in, const int* in_sizes, int n_in,
                              void* d_out, int out_size, void* d_ws, size_t ws_size,
                              hipStream_t stream) {
    const float4* priors    = (const float4*)d_in[0];   // (P, 4) f32
    const float4* gt_boxes  = (const float4*)d_in[1];   // (B, T, 4) f32
    const int*    gt_labels = (const int*)d_in[2];      // (B, T) i32

    const int P = in_sizes[0] / 4;
    const int B = in_sizes[2] / T_GT;

    float* out_loc = (float*)d_out;
    float* out_lbl = out_loc + (size_t)B * P * 4;

    const int NG = (P + 256 * KP - 1) / (256 * KP);   // blocks per image (98)
    u64* part = (u64*)d_ws;   // (B, NG, 64) u64 — fully overwritten, no memset

    dim3 g(NG, B);
    fused_match<<<g, 256, 0, stream>>>(priors, gt_boxes, gt_labels, part,
                                       out_loc, out_lbl, P, NG);
    fixup_kernel<<<B, 256, 0, stream>>>(priors, gt_boxes, gt_labels, part,
                                        out_loc, out_lbl, P, NG);
}

// Round 6
// 164.788 us; speedup vs baseline: 1.4715x; 1.0731x over previous
//
#include <hip/hip_runtime.h>

#define T_GT 64
#define KP 2          // priors per thread
#define TPB 256

typedef unsigned int u32;
typedef unsigned long long u64;

// ---------------------------------------------------------------------------
// Fused kernel: thread = (b, KP consecutive priors). Each IoU computed ONCE:
//   - match: per-prior argmax over t -> pack (q_bits<<32)|(63-t), u64 max
//     (first-index tie-break independent of visit order)
//   - best_prior: per-(b,t) argmax over p: lane l at step i owns t=(l+i)&63
//     exclusively within its wave -> fire-and-forget LDS atomicMax into a
//     per-wave per-t partial (ds_max_u64 no-rtn: nothing on the critical
//     path). Pack (q_bits<<32)|(~p) = numpy first-index, order-independent.
//     Block partials written non-atomically to ws (no global memset needed).
// All selection-critical FP ops use __f*_rn intrinsics: exact IEEE ops, no
// fma contraction -> bit-identical to the numpy reference, deterministic.
// ---------------------------------------------------------------------------
__global__ void __launch_bounds__(256)
fused_match(const float4* __restrict__ priors,
            const float4* __restrict__ gt_boxes,
            const int* __restrict__ gt_labels,
            u64* __restrict__ part,        // (B, NG, 64) block partials
            float* __restrict__ out_loc,   // (B, P, 4)
            float* __restrict__ out_lbl,   // (B, P) as float
            int P, int NG) {
    __shared__ float4 s_gt[T_GT];
    __shared__ float  s_ga[T_GT];
    __shared__ u64    s_best[4][T_GT];

    const int tid  = threadIdx.x;
    const int lane = tid & 63;
    const int wv   = tid >> 6;
    const int b    = blockIdx.y;
    const int tb   = blockIdx.x * TPB + tid;

    if (tid < T_GT) {
        const float4 gb = gt_boxes[b * T_GT + tid];
        s_gt[tid] = gb;
        s_ga[tid] = __fmul_rn(__fsub_rn(gb.z, gb.x), __fsub_rn(gb.w, gb.y));
    }
    s_best[wv][lane] = 0;
    __syncthreads();

    // load KP consecutive priors; precompute xyxy + area (ref op order)
    float px0[KP], py0[KP], px1[KP], py1[KP], pa[KP];
    u32 pc[KP];
    #pragma unroll
    for (int j = 0; j < KP; ++j) {
        const int p = min(tb * KP + j, P - 1);  // clamp: dup of P-1 is a
        pc[j] = (u32)p;                         // no-op for max reductions
        const float4 pr = priors[p];
        px0[j] = __fsub_rn(pr.x, __fmul_rn(0.5f, pr.z));
        py0[j] = __fsub_rn(pr.y, __fmul_rn(0.5f, pr.w));
        px1[j] = __fadd_rn(pr.x, __fmul_rn(0.5f, pr.z));
        py1[j] = __fadd_rn(pr.y, __fmul_rn(0.5f, pr.w));
        pa[j]  = __fmul_rn(__fsub_rn(px1[j], px0[j]), __fsub_rn(py1[j], py0[j]));
    }

    u64 mbest[KP];
    #pragma unroll
    for (int j = 0; j < KP; ++j) mbest[j] = 0;

    #pragma unroll 4
    for (int i = 0; i < T_GT; ++i) {
        const int t = (lane + i) & 63;          // bijective in lane each step
        const float4 gb  = s_gt[t];             // conflict-free b128
        const float  gar = s_ga[t];
        u64 step = 0;
        #pragma unroll
        for (int j = 0; j < KP; ++j) {
            const float ltx = fmaxf(gb.x, px0[j]);
            const float lty = fmaxf(gb.y, py0[j]);
            const float rbx = fminf(gb.z, px1[j]);
            const float rby = fminf(gb.w, py1[j]);
            const float wx = fmaxf(__fsub_rn(rbx, ltx), 0.0f);
            const float wy = fmaxf(__fsub_rn(rby, lty), 0.0f);
            const float inter = __fmul_rn(wx, wy);
            const float uni = __fsub_rn(__fadd_rn(gar, pa[j]), inter);
            const float q = __fdiv_rn(inter, uni);     // IEEE f32 divide
            const u64 qh = (u64)__float_as_uint(q) << 32;
            const u64 mp = qh | (u32)(63 - t);
            if (mp > mbest[j]) mbest[j] = mp;
            const u64 ap = qh | (u64)(0xFFFFFFFFu - pc[j]);
            if (ap > step) step = ap;
        }
        atomicMax(&s_best[wv][t], step);        // ds_max_u64, fire-and-forget
    }

    __syncthreads();
    if (tid < T_GT) {
        u64 m = s_best[0][tid];
        #pragma unroll
        for (int w = 1; w < 4; ++w) {
            const u64 v = s_best[w][tid];
            if (v > m) m = v;
        }
        part[((size_t)b * NG + blockIdx.x) * T_GT + tid] = m;
    }

    // epilogue: decode match, encode loc with the ORIGINAL prior values
    // (reload is L1-hot; keeps loc math identical to the reference)
    #pragma unroll
    for (int j = 0; j < KP; ++j) {
        const int p = tb * KP + j;
        if (p >= P) break;
        const int   t_best = 63 - (int)(mbest[j] & 63u);
        const float q_best = __uint_as_float((u32)(mbest[j] >> 32));
        const int   lbl = (q_best < 0.5f) ? 0 : gt_labels[b * T_GT + t_best];

        const float4 pr = priors[p];
        const float4 mb = s_gt[t_best];
        const float  bcx = (mb.x + mb.z) * 0.5f;
        const float  bcy = (mb.y + mb.w) * 0.5f;
        const float  bw  = mb.z - mb.x;
        const float  bh  = mb.w - mb.y;

        float4 loc;
        loc.x = (bcx - pr.x) / (0.1f * pr.z);
        loc.y = (bcy - pr.y) / (0.1f * pr.w);
        loc.z = logf(bw / pr.z) / 0.2f;
        loc.w = logf(bh / pr.w) / 0.2f;

        ((float4*)out_loc)[(size_t)b * P + p] = loc;
        out_lbl[(size_t)b * P + p] = (float)lbl;
    }
}

// ---------------------------------------------------------------------------
// Fixup: reduce block partials per (b,t), then apply
// matches[best_prior[t]] = t (numpy last-wins on duplicate best_prior;
// matched_val = 2.0 so the label is always kept). One block per image.
// All waves alive at every barrier.
// ---------------------------------------------------------------------------
__global__ void __launch_bounds__(256)
fixup_kernel(const float4* __restrict__ priors,
             const float4* __restrict__ gt_boxes,
             const int* __restrict__ gt_labels,
             const u64* __restrict__ part,
             float* __restrict__ out_loc,
             float* __restrict__ out_lbl,
             int P, int NG) {
    __shared__ u64 s_m[4][T_GT];
    __shared__ u32 s_p[T_GT];
    const int b   = blockIdx.x;
    const int tid = threadIdx.x;
    const int t   = tid & 63;
    const int w   = tid >> 6;

    u64 m = 0;
    for (int g = w; g < NG; g += 4) {
        const u64 v = part[((size_t)b * NG + g) * T_GT + t];
        if (v > m) m = v;
    }
    s_m[w][t] = m;
    __syncthreads();
    if (tid < T_GT) {
        m = s_m[0][t];
        #pragma unroll
        for (int i = 1; i < 4; ++i) {
            const u64 v = s_m[i][t];
            if (v > m) m = v;
        }
        s_p[t] = 0xFFFFFFFFu - (u32)(m & 0xFFFFFFFFull);
    }
    __syncthreads();
    if (tid >= T_GT) return;

    const u32 p = s_p[t];
    for (int u = t + 1; u < T_GT; ++u)
        if (s_p[u] == p) return;      // a later t overrides this prior

    const float4 pr = priors[p];
    const float4 mb = gt_boxes[b * T_GT + t];
    const float  bcx = (mb.x + mb.z) * 0.5f;
    const float  bcy = (mb.y + mb.w) * 0.5f;
    const float  bw  = mb.z - mb.x;
    const float  bh  = mb.w - mb.y;

    float4 loc;
    loc.x = (bcx - pr.x) / (0.1f * pr.z);
    loc.y = (bcy - pr.y) / (0.1f * pr.w);
    loc.z = logf(bw / pr.z) / 0.2f;
    loc.w = logf(bh / pr.w) / 0.2f;

    ((float4*)out_loc)[(size_t)b * P + p] = loc;
    out_lbl[(size_t)b * P + p] = (float)gt_labels[b * T_GT + t];
}

extern "C" void kernel_launch(void* const* d_in, const int* in_sizes, int n_in,
                              void* d_out, int out_size, void* d_ws, size_t ws_size,
                              hipStream_t stream) {
    const float4* priors    = (const float4*)d_in[0];   // (P, 4) f32
    const float4* gt_boxes  = (const float4*)d_in[1];   // (B, T, 4) f32
    const int*    gt_labels = (const int*)d_in[2];      // (B, T) i32

    const int P = in_sizes[0] / 4;
    const int B = in_sizes[2] / T_GT;

    float* out_loc = (float*)d_out;
    float* out_lbl = out_loc + (size_t)B * P * 4;

    const int NG = (P + TPB * KP - 1) / (TPB * KP);   // blocks per image (196)
    u64* part = (u64*)d_ws;   // (B, NG, 64) u64 — fully overwritten, no memset

    dim3 g(NG, B);
    fused_match<<<g, TPB, 0, stream>>>(priors, gt_boxes, gt_labels, part,
                                       out_loc, out_lbl, P, NG);
    fixup_kernel<<<B, TPB, 0, stream>>>(priors, gt_boxes, gt_labels, part,
                                        out_loc, out_lbl, P, NG);
}

// Round 7
// 134.166 us; speedup vs baseline: 1.8074x; 1.2282x over previous
//
#include <hip/hip_runtime.h>

#define T_GT 64
#define KP 2          // priors per thread
#define TPB 256

typedef unsigned int u32;
typedef unsigned long long u64;

// ---------------------------------------------------------------------------
// Fused kernel, screened: thread = (b, KP consecutive priors).
// Phase 1: per t, overlap screen using the SAME __f*_rn ops as the IoU, so
//   pred == (inter > 0) exactly. Bitmask built with t descending => bit k of
//   (mhi,mlo) is t, and ctz-ascending iteration visits t in increasing order
//   (preserves numpy first-index tie-break).
// Phase 2: full IoU only for overlapping t (~5% of pairs):
//   - match: pack (q_bits<<32)|(63-t), u64 max; init {q=0,t=0} == numpy
//     argmax of an all-zero row (all screened-out candidates have q==+0.0).
//   - best_prior: per-candidate LDS atomicMax of (q_bits<<32)|(~p) into the
//     per-wave per-t slot; slot init {q=0,p=0} == numpy argmax of an all-zero
//     column. Block partials -> ws, no global memset.
// All selection-critical FP ops are __f*_rn: exact IEEE, no contraction ->
// selection bit-identical to the numpy reference.
// ---------------------------------------------------------------------------
__global__ void __launch_bounds__(256)
fused_match(const float4* __restrict__ priors,
            const float4* __restrict__ gt_boxes,
            const int* __restrict__ gt_labels,
            u64* __restrict__ part,        // (B, NG, 64) block partials
            float* __restrict__ out_loc,   // (B, P, 4)
            float* __restrict__ out_lbl,   // (B, P) as float
            int P, int NG) {
    __shared__ float4 s_gt[T_GT];
    __shared__ float  s_ga[T_GT];
    __shared__ int    s_lbl[T_GT];
    __shared__ u64    s_best[4][T_GT];

    const int tid  = threadIdx.x;
    const int lane = tid & 63;
    const int wv   = tid >> 6;
    const int b    = blockIdx.y;
    const int tb   = blockIdx.x * TPB + tid;

    if (tid < T_GT) {
        const float4 gb = gt_boxes[b * T_GT + tid];
        s_gt[tid]  = gb;
        s_ga[tid]  = __fmul_rn(__fsub_rn(gb.z, gb.x), __fsub_rn(gb.w, gb.y));
        s_lbl[tid] = gt_labels[b * T_GT + tid];
    }
    s_best[wv][lane] = (u64)0xFFFFFFFFu;   // {q=+0.0, p=0} default
    __syncthreads();

    // load KP consecutive priors; precompute xyxy + area (ref op order)
    float px0[KP], py0[KP], px1[KP], py1[KP], pa[KP];
    float4 prr[KP];
    u32 pc[KP];
    #pragma unroll
    for (int j = 0; j < KP; ++j) {
        const int p = min(tb * KP + j, P - 1);  // clamp: dup of P-1 harmless
        pc[j] = (u32)p;
        const float4 pr = priors[p];
        prr[j] = pr;
        px0[j] = __fsub_rn(pr.x, __fmul_rn(0.5f, pr.z));
        py0[j] = __fsub_rn(pr.y, __fmul_rn(0.5f, pr.w));
        px1[j] = __fadd_rn(pr.x, __fmul_rn(0.5f, pr.z));
        py1[j] = __fadd_rn(pr.y, __fmul_rn(0.5f, pr.w));
        pa[j]  = __fmul_rn(__fsub_rn(px1[j], px0[j]), __fsub_rn(py1[j], py0[j]));
    }

    // ---- phase 1: overlap masks (t descending -> bit k == t offset) ----
    u32 mhi[KP], mlo[KP];
    #pragma unroll
    for (int j = 0; j < KP; ++j) { mhi[j] = 0; mlo[j] = 0; }

    #pragma unroll 8
    for (int t = 63; t >= 32; --t) {
        const float4 gb = s_gt[t];              // uniform -> LDS broadcast
        #pragma unroll
        for (int j = 0; j < KP; ++j) {
            const float sx = __fsub_rn(fminf(gb.z, px1[j]), fmaxf(gb.x, px0[j]));
            const float sy = __fsub_rn(fminf(gb.w, py1[j]), fmaxf(gb.y, py0[j]));
            mhi[j] = mhi[j] + mhi[j] + (fminf(sx, sy) > 0.0f ? 1u : 0u);
        }
    }
    #pragma unroll 8
    for (int t = 31; t >= 0; --t) {
        const float4 gb = s_gt[t];
        #pragma unroll
        for (int j = 0; j < KP; ++j) {
            const float sx = __fsub_rn(fminf(gb.z, px1[j]), fmaxf(gb.x, px0[j]));
            const float sy = __fsub_rn(fminf(gb.w, py1[j]), fmaxf(gb.y, py0[j]));
            mlo[j] = mlo[j] + mlo[j] + (fminf(sx, sy) > 0.0f ? 1u : 0u);
        }
    }

    // ---- phase 2: evaluate candidates only ----
    u64 mbest[KP];
    #pragma unroll
    for (int j = 0; j < KP; ++j) mbest[j] = 63u;   // {q=0, rt=63} == t 0

    #pragma unroll
    for (int j = 0; j < KP; ++j) {
        #pragma unroll
        for (int half = 0; half < 2; ++half) {
            u32 mask = half ? mhi[j] : mlo[j];
            const int tbase = half ? 32 : 0;
            while (mask) {                        // ascending t per lane
                const int t = tbase + __builtin_ctz(mask);
                mask &= mask - 1;
                const float4 gb  = s_gt[t];
                const float  gar = s_ga[t];
                const float ltx = fmaxf(gb.x, px0[j]);
                const float lty = fmaxf(gb.y, py0[j]);
                const float rbx = fminf(gb.z, px1[j]);
                const float rby = fminf(gb.w, py1[j]);
                const float wx = fmaxf(__fsub_rn(rbx, ltx), 0.0f);
                const float wy = fmaxf(__fsub_rn(rby, lty), 0.0f);
                const float inter = __fmul_rn(wx, wy);
                const float uni = __fsub_rn(__fadd_rn(gar, pa[j]), inter);
                const float q = __fdiv_rn(inter, uni);    // IEEE f32 divide
                const u64 qh = (u64)__float_as_uint(q) << 32;
                const u64 mp = qh | (u32)(63 - t);
                if (mp > mbest[j]) mbest[j] = mp;
                atomicMax(&s_best[wv][t], qh | (u64)(0xFFFFFFFFu - pc[j]));
            }
        }
    }

    __syncthreads();
    if (tid < T_GT) {
        u64 m = s_best[0][tid];
        #pragma unroll
        for (int w = 1; w < 4; ++w) {
            const u64 v = s_best[w][tid];
            if (v > m) m = v;
        }
        part[((size_t)b * NG + blockIdx.x) * T_GT + tid] = m;
    }

    // ---- epilogue: decode match, encode loc ----
    #pragma unroll
    for (int j = 0; j < KP; ++j) {
        const int p = tb * KP + j;
        if (p >= P) break;
        const int   t_best = 63 - (int)(mbest[j] & 63u);
        const float q_best = __uint_as_float((u32)(mbest[j] >> 32));
        const int   lbl = (q_best < 0.5f) ? 0 : s_lbl[t_best];

        const float4 pr = prr[j];
        const float4 mb = s_gt[t_best];
        const float  bcx = (mb.x + mb.z) * 0.5f;
        const float  bcy = (mb.y + mb.w) * 0.5f;
        const float  bw  = mb.z - mb.x;
        const float  bh  = mb.w - mb.y;

        float4 loc;
        loc.x = (bcx - pr.x) / (0.1f * pr.z);
        loc.y = (bcy - pr.y) / (0.1f * pr.w);
        loc.z = logf(bw / pr.z) / 0.2f;
        loc.w = logf(bh / pr.w) / 0.2f;

        ((float4*)out_loc)[(size_t)b * P + p] = loc;
        out_lbl[(size_t)b * P + p] = (float)lbl;
    }
}

// ---------------------------------------------------------------------------
// Fixup: reduce block partials per (b,t), then apply
// matches[best_prior[t]] = t (numpy last-wins on duplicate best_prior;
// matched_val = 2.0 so the label is always kept). One block per image.
// ---------------------------------------------------------------------------
__global__ void __launch_bounds__(256)
fixup_kernel(const float4* __restrict__ priors,
             const float4* __restrict__ gt_boxes,
             const int* __restrict__ gt_labels,
             const u64* __restrict__ part,
             float* __restrict__ out_loc,
             float* __restrict__ out_lbl,
             int P, int NG) {
    __shared__ u64 s_m[4][T_GT];
    __shared__ u32 s_p[T_GT];
    const int b   = blockIdx.x;
    const int tid = threadIdx.x;
    const int t   = tid & 63;
    const int w   = tid >> 6;

    u64 m = 0;
    for (int g = w; g < NG; g += 4) {
        const u64 v = part[((size_t)b * NG + g) * T_GT + t];
        if (v > m) m = v;
    }
    s_m[w][t] = m;
    __syncthreads();
    if (tid < T_GT) {
        m = s_m[0][t];
        #pragma unroll
        for (int i = 1; i < 4; ++i) {
            const u64 v = s_m[i][t];
            if (v > m) m = v;
        }
        s_p[t] = 0xFFFFFFFFu - (u32)(m & 0xFFFFFFFFull);
    }
    __syncthreads();
    if (tid >= T_GT) return;

    const u32 p = s_p[t];
    for (int u = t + 1; u < T_GT; ++u)
        if (s_p[u] == p) return;      // a later t overrides this prior

    const float4 pr = priors[p];
    const float4 mb = gt_boxes[b * T_GT + t];
    const float  bcx = (mb.x + mb.z) * 0.5f;
    const float  bcy = (mb.y + mb.w) * 0.5f;
    const float  bw  = mb.z - mb.x;
    const float  bh  = mb.w - mb.y;

    float4 loc;
    loc.x = (bcx - pr.x) / (0.1f * pr.z);
    loc.y = (bcy - pr.y) / (0.1f * pr.w);
    loc.z = logf(bw / pr.z) / 0.2f;
    loc.w = logf(bh / pr.w) / 0.2f;

    ((float4*)out_loc)[(size_t)b * P + p] = loc;
    out_lbl[(size_t)b * P + p] = (float)gt_labels[b * T_GT + t];
}

extern "C" void kernel_launch(void* const* d_in, const int* in_sizes, int n_in,
                              void* d_out, int out_size, void* d_ws, size_t ws_size,
                              hipStream_t stream) {
    const float4* priors    = (const float4*)d_in[0];   // (P, 4) f32
    const float4* gt_boxes  = (const float4*)d_in[1];   // (B, T, 4) f32
    const int*    gt_labels = (const int*)d_in[2];      // (B, T) i32

    const int P = in_sizes[0] / 4;
    const int B = in_sizes[2] / T_GT;

    float* out_loc = (float*)d_out;
    float* out_lbl = out_loc + (size_t)B * P * 4;

    const int NG = (P + TPB * KP - 1) / (TPB * KP);   // blocks per image (196)
    u64* part = (u64*)d_ws;   // (B, NG, 64) u64 — fully overwritten, no memset

    dim3 g(NG, B);
    fused_match<<<g, TPB, 0, stream>>>(priors, gt_boxes, gt_labels, part,
                                       out_loc, out_lbl, P, NG);
    fixup_kernel<<<B, TPB, 0, stream>>>(priors, gt_boxes, gt_labels, part,
                                        out_loc, out_lbl, P, NG);
}